// Round 7
// baseline (774.899 us; speedup 1.0000x reference)
//
#include <hip/hip_runtime.h>
#include <hip/hip_bf16.h>

// Bahdanau attention, MI355X. B=32, S=2048, H=1024, HL=2048.
// d_out: context[32,1,1024] ++ weights[32,1,2048]  (fp32)
//
// R12: kb16 pre-pass DELETED (384MB round trip, ~115us). Score GEMM stages
// A directly from fp32 keys via global_load_lds, storing each 16KB A-tile
// as TWO 8KB subtiles with 64B rows (k-halves). 64B rows reproduce the
// proven bf16 bank structure (slot8 = (row&1)*4 + slot4) -> conflict-free,
// unlike R10's 128B rows (slot-only banking, 8-way pileup). Inverse XOR
// permutation applied to per-lane GLOBAL source; fp32->bf16 at frag-read
// (16 cvt_pk hidden under 16 MFMA). Tile = proven R8 128x128 / 48KB LDS.
// pre_k = qproj + uat only. ctx sper=32 (2048 blocks).
//
// ws layout: qws 128K | uat 2M | score 256K

typedef __attribute__((ext_vector_type(8))) short short8;
typedef __attribute__((ext_vector_type(4))) float floatx4;

typedef const __attribute__((address_space(1))) unsigned int gu32;
typedef __attribute__((address_space(3))) unsigned int lu32;

__device__ __forceinline__ unsigned short f2bf(float f) {
    union { float f; unsigned int u; } c; c.f = f;
    unsigned int u = c.u + 0x7fffu + ((c.u >> 16) & 1u);  // RNE
    return (unsigned short)(u >> 16);
}

// two fp32 -> packed bf16 pair (lo in bits 0..15), RNE either way
__device__ __forceinline__ unsigned int f2bf2(float lo, float hi) {
#if __has_builtin(__builtin_amdgcn_cvt_pk_bf16_f32)
    auto r = __builtin_amdgcn_cvt_pk_bf16_f32(lo, hi);
    unsigned int u; __builtin_memcpy(&u, &r, 4);
    return u;
#else
    return (unsigned int)f2bf(lo) | ((unsigned int)f2bf(hi) << 16);
#endif
}

// async global->LDS, 16B per lane; lane i's data lands at ldsbase + i*16.
// LDS dest must be wave-uniform; per-lane scatter goes on the GLOBAL side.
__device__ __forceinline__ void gld16(const void* g, const void* l) {
    __builtin_amdgcn_global_load_lds(
        (gu32*)(uintptr_t)g,
        (lu32*)(unsigned int)(uintptr_t)l,
        16, 0, 0);
}

// ---- K1: fused prep: qproj (blocks 0..511) + uat (512..767) ----
__global__ __launch_bounds__(256) void pre_k(
    const float* __restrict__ query, const float* __restrict__ Wa,
    const float* __restrict__ Wab, const float* __restrict__ Uab,
    const float* __restrict__ Ua,
    float* __restrict__ qws, unsigned short* __restrict__ uat)
{
    __shared__ char smem[12288];
    const int tid = threadIdx.x;
    if (blockIdx.x < 512) {
        float* qs  = (float*)smem;          // 2048 f
        float* red = (float*)(smem + 8192); // 1024 f
        const int b = blockIdx.x >> 4, hc = blockIdx.x & 15;
        #pragma unroll
        for (int i = 0; i < 8; i++) qs[tid + 256*i] = query[b*2048 + tid + 256*i];
        __syncthreads();
        const int hq = tid & 15;      // h-quad within 64-h tile
        const int dg = tid >> 4;      // d-group (128 d each)
        const float4* wp = reinterpret_cast<const float4*>(Wa + (size_t)(dg*128)*1024 + hc*64 + hq*4);
        const float* qp = qs + dg*128;
        float4 a0; a0.x = a0.y = a0.z = a0.w = 0.f;
        float4 a1; a1.x = a1.y = a1.z = a1.w = 0.f;
        #pragma unroll 4
        for (int d = 0; d < 128; d += 2) {
            float q0 = qp[d], q1 = qp[d+1];
            float4 w0 = wp[(size_t)d*256];
            float4 w1 = wp[(size_t)(d+1)*256];
            a0.x += q0*w0.x; a0.y += q0*w0.y; a0.z += q0*w0.z; a0.w += q0*w0.w;
            a1.x += q1*w1.x; a1.y += q1*w1.y; a1.z += q1*w1.z; a1.w += q1*w1.w;
        }
        a0.x += a1.x; a0.y += a1.y; a0.z += a1.z; a0.w += a1.w;
        *reinterpret_cast<float4*>(red + dg*64 + hq*4) = a0;
        __syncthreads();
        if (tid < 64) {
            float v = 0.f;
            #pragma unroll
            for (int g = 0; g < 16; g++) v += red[g*64 + tid];
            int hh = hc*64 + tid;
            qws[b*1024 + hh] = v + Wab[hh] + Uab[hh];
        }
    } else {
        typedef unsigned short row_t[65];
        row_t* t = (row_t*)smem;            // 64 x 65 ushort
        const int q = blockIdx.x - 512;
        const int x = tid & 63, yy = tid >> 6;
        const int d0 = (q >> 4)*64, h0 = (q & 15)*64;
        #pragma unroll
        for (int i = 0; i < 16; i++) {
            int y = yy*16 + i;
            t[y][x] = f2bf(Ua[(size_t)(d0+y)*1024 + h0 + x]);
        }
        __syncthreads();
        #pragma unroll
        for (int i = 0; i < 16; i++) {
            int y = yy*16 + i;
            uat[(size_t)(h0+y)*1024 + d0 + x] = t[x][y];
        }
    }
}

// ---- K3: score GEMM 128(s) x 128(h), fp32 A direct + bf16 B, gld16 both ----
// A tile (128 rows x 32 fp32 = 16KB) stored as 2 subtiles (k-halves of 16
// floats), each with 64B rows of 4 fp32-chunks (16B): subtile st, row r,
// slot4 sl holds chunk c4 = sl ^ ((r>>1)&3)  [same bank structure as the
// proven bf16 scheme -> conflict-free].
// Staging: 4 gld16/tile, LINEAR dest chunk D = it*256+tid; inverse perm on
// global source: row=(it&1)*64+(tid>>2), st=it>>1, c4=(tid&3)^((tid>>3)&3).
// Frag read: quad q -> subtile q>>1, chunks cb,cb+1 (cb=(2q)&3) at slots
// (cb^rr),(cb+1^rr); 2x float4 ds_read + 4 cvt_pk -> af.
// B (bf16 uat): proven R8 scheme, unchanged.
// Double-buffered, ONE barrier per K-step; 16 MFMA/thread/K-step.
// Epilogue: tanh + Va dot + atomicAdd into score[32][2048].
__global__ __launch_bounds__(256) void score_gemm_fast(
    const float* __restrict__ keys,           // [32][2048][1024] fp32
    const unsigned short* __restrict__ uat,   // [1024][1024] bf16 [h][d]
    const float* __restrict__ qws,            // [32][1024]
    const float* __restrict__ Va,             // [1024]
    float* __restrict__ score)                // [32][2048] (pre-zeroed)
{
    __shared__ float          aSf[2][128*32]; // 2 x 16KB
    __shared__ unsigned short bS[2][128*32];  // 2 x 8KB
    const int tid = threadIdx.x;
    const int b  = blockIdx.z;
    const int s0 = blockIdx.x * 128;
    const int h0 = blockIdx.y * 128;
    const int lane = tid & 63, wave = tid >> 6;
    const int quad = lane >> 4, l15 = lane & 15;
    const int wm = (wave & 1) * 64, wn = (wave >> 1) * 64;

    // B-staging source (runtime-permuted, proven R8)
    const int srow = lane >> 2;
    const int schunk = (lane & 3) ^ ((srow >> 1) & 3);
    const int c0 = wave*2, c1 = wave*2 + 1;
    const unsigned short* ubase = uat + (size_t)h0*1024;
    const size_t boff0 = (size_t)(c0*16 + srow)*1024 + schunk*8;
    const size_t boff1 = (size_t)(c1*16 + srow)*1024 + schunk*8;

    // A-staging source (fp32, inverse-permuted): instr it covers chunk
    // D = it*256+tid -> st = it>>1, row = (it&1)*64 + (tid>>2),
    // slot4 = tid&3, content chunk c4 = (tid&3) ^ ((tid>>3)&3).
    const float* kA = keys + (size_t)(b*2048 + s0)*1024;
    const int arh = tid >> 2;                       // row within 64-half
    const int ac4 = (tid & 3) ^ ((tid >> 3) & 3);   // source chunk
    size_t aoff[4];
    #pragma unroll
    for (int it = 0; it < 4; it++)
        aoff[it] = (size_t)((it & 1)*64 + arh)*1024 + (size_t)(it >> 1)*16 + ac4*4;

    floatx4 acc[4][4];
    #pragma unroll
    for (int i = 0; i < 4; i++)
        #pragma unroll
        for (int j = 0; j < 4; j++) acc[i][j] = (floatx4)0.0f;

    // per-frag read constants
    const int fst = (quad >> 1) * 2048;       // subtile float offset
    const int cb  = (2*quad) & 3;             // chunk base within subtile

    // ---- prologue: stage tile 0 into buffer 0 ----
    #pragma unroll
    for (int it = 0; it < 4; it++)
        gld16(kA + aoff[it], (unsigned short*)aSf[0] + it*2048 + wave*512);
    gld16(ubase + boff0, bS[0] + c0*512);
    gld16(ubase + boff1, bS[0] + c1*512);
    __syncthreads();

    int cur = 0;
    for (int kt = 0; kt < 31; ++kt) {
        const int nxt = cur ^ 1;
        const int k1 = (kt + 1) << 5;   // element offset (fp32 A, bf16 B)

        // prefetch tile kt+1 into idle buffer (6 async instrs)
        #pragma unroll
        for (int it = 0; it < 4; it++)
            gld16(kA + aoff[it] + k1, (unsigned short*)aSf[nxt] + it*2048 + wave*512);
        gld16(ubase + boff0 + k1, bS[nxt] + c0*512);
        gld16(ubase + boff1 + k1, bS[nxt] + c1*512);

        // compute tile kt from buf cur
        short8 af[4], bf8[4];
        #pragma unroll
        for (int i = 0; i < 4; i++) {
            int row = wm + 16*i + l15;
            int rr  = (row >> 1) & 3;
            const float* sub = aSf[cur] + fst + row*16;
            float4 v0 = *reinterpret_cast<const float4*>(sub + ((cb ^ rr) << 2));
            float4 v1 = *reinterpret_cast<const float4*>(sub + (((cb + 1) ^ rr) << 2));
            union { uint4 u; short8 s; } cv;
            cv.u.x = f2bf2(v0.x, v0.y); cv.u.y = f2bf2(v0.z, v0.w);
            cv.u.z = f2bf2(v1.x, v1.y); cv.u.w = f2bf2(v1.z, v1.w);
            af[i] = cv.s;
        }
        #pragma unroll
        for (int j = 0; j < 4; j++) {
            int row = wn + 16*j + l15;
            bf8[j] = *reinterpret_cast<const short8*>(bS[cur] + row*32 + ((quad ^ ((row>>1)&3)) * 8));
        }
        #pragma unroll
        for (int i = 0; i < 4; i++)
            #pragma unroll
            for (int j = 0; j < 4; j++)
                acc[i][j] = __builtin_amdgcn_mfma_f32_16x16x32_bf16(af[i], bf8[j], acc[i][j], 0, 0, 0);

        __syncthreads();   // drains prefetch vmcnt + frag lgkm; one barrier/K-step
        cur = nxt;
    }

    // ---- last tile: compute only ----
    {
        short8 af[4], bf8[4];
        #pragma unroll
        for (int i = 0; i < 4; i++) {
            int row = wm + 16*i + l15;
            int rr  = (row >> 1) & 3;
            const float* sub = aSf[cur] + fst + row*16;
            float4 v0 = *reinterpret_cast<const float4*>(sub + ((cb ^ rr) << 2));
            float4 v1 = *reinterpret_cast<const float4*>(sub + (((cb + 1) ^ rr) << 2));
            union { uint4 u; short8 s; } cv;
            cv.u.x = f2bf2(v0.x, v0.y); cv.u.y = f2bf2(v0.z, v0.w);
            cv.u.z = f2bf2(v1.x, v1.y); cv.u.w = f2bf2(v1.z, v1.w);
            af[i] = cv.s;
        }
        #pragma unroll
        for (int j = 0; j < 4; j++) {
            int row = wn + 16*j + l15;
            bf8[j] = *reinterpret_cast<const short8*>(bS[cur] + row*32 + ((quad ^ ((row>>1)&3)) * 8));
        }
        #pragma unroll
        for (int i = 0; i < 4; i++)
            #pragma unroll
            for (int j = 0; j < 4; j++)
                acc[i][j] = __builtin_amdgcn_mfma_f32_16x16x32_bf16(af[i], bf8[j], acc[i][j], 0, 0, 0);
    }

    // epilogue: p[s] = sum_n Va[n]*tanh(q[n]+k[s,n]); C-layout: n=lane&15, m=quad*4+reg
    float qv[4], vav[4];
    #pragma unroll
    for (int j = 0; j < 4; j++) {
        int n = h0 + wn + 16*j + l15;
        qv[j]  = qws[b*1024 + n];
        vav[j] = Va[n];
    }
    #pragma unroll
    for (int i = 0; i < 4; i++) {
        #pragma unroll
        for (int r = 0; r < 4; r++) {
            float p = 0.f;
            #pragma unroll
            for (int j = 0; j < 4; j++) {
                float x = qv[j] + acc[i][j][r];
                float e = __expf(2.f * x);                       // tanh = 1 - 2/(e^{2x}+1)
                float t = 1.f - 2.f * __builtin_amdgcn_rcpf(e + 1.f);
                p += vav[j] * t;
            }
            #pragma unroll
            for (int off = 1; off < 16; off <<= 1) p += __shfl_xor(p, off, 64);
            if (l15 == 0) {
                int m = wm + 16*i + quad*4 + r;
                atomicAdd(score + (size_t)b*2048 + s0 + m, p);
            }
        }
    }
}

// ---- K4: softmax over s per batch (single-pass; score pre-reduced) ----
__global__ __launch_bounds__(256) void softmax_k(const float* __restrict__ score,
                                                 float* __restrict__ out_w)
{
    const int tid = threadIdx.x;
    const int b = blockIdx.x;
    __shared__ float wred[4], wred2[4];
    float sc[8];
    float mx = -3.0e38f;
    #pragma unroll
    for (int i = 0; i < 8; i++) {
        sc[i] = score[(size_t)b*2048 + tid + 256*i];
        mx = fmaxf(mx, sc[i]);
    }
    #pragma unroll
    for (int off = 32; off >= 1; off >>= 1) mx = fmaxf(mx, __shfl_xor(mx, off, 64));
    if ((tid & 63) == 0) wred[tid >> 6] = mx;
    __syncthreads();
    mx = fmaxf(fmaxf(wred[0], wred[1]), fmaxf(wred[2], wred[3]));
    float e[8]; float lsum = 0.f;
    #pragma unroll
    for (int i = 0; i < 8; i++) { e[i] = __expf(sc[i] - mx); lsum += e[i]; }
    #pragma unroll
    for (int off = 32; off >= 1; off >>= 1) lsum += __shfl_xor(lsum, off, 64);
    if ((tid & 63) == 0) wred2[tid >> 6] = lsum;
    __syncthreads();
    float inv = 1.0f / (wred2[0] + wred2[1] + wred2[2] + wred2[3]);
    #pragma unroll
    for (int i = 0; i < 8; i++) out_w[b*2048 + tid + 256*i] = e[i] * inv;
}

// ---- K5: context accumulated directly into out_ctx via atomics ----
__global__ __launch_bounds__(256) void ctx_k(const float* __restrict__ keys,
                                             const float* __restrict__ w,
                                             float* __restrict__ out_ctx, int sper)
{
    const int tid = threadIdx.x;
    const int b = blockIdx.x, sc = blockIdx.y;
    const float4* k4 = reinterpret_cast<const float4*>(keys) + (size_t)(b*2048 + sc*sper)*256;
    const float* wp = w + b*2048 + sc*sper;
    float4 a; a.x = a.y = a.z = a.w = 0.f;
    #pragma unroll 4
    for (int s = 0; s < sper; s++) {
        float wv = wp[s];
        float4 kv = k4[(size_t)s*256 + tid];
        a.x += wv*kv.x; a.y += wv*kv.y; a.z += wv*kv.z; a.w += wv*kv.w;
    }
    float* o = out_ctx + (size_t)b*1024 + tid*4;
    atomicAdd(o + 0, a.x);
    atomicAdd(o + 1, a.y);
    atomicAdd(o + 2, a.z);
    atomicAdd(o + 3, a.w);
}

extern "C" void kernel_launch(void* const* d_in, const int* in_sizes, int n_in,
                              void* d_out, int out_size, void* d_ws, size_t ws_size,
                              hipStream_t stream)
{
    const float* query = (const float*)d_in[0];
    const float* keys  = (const float*)d_in[1];
    const float* Wa_w  = (const float*)d_in[2];
    const float* Wa_b  = (const float*)d_in[3];
    const float* Ua_w  = (const float*)d_in[4];
    const float* Ua_b  = (const float*)d_in[5];
    const float* Va_w  = (const float*)d_in[6];
    // d_in[7] (Va_b) is a uniform shift on scores -> softmax-invariant; unused.

    char* ws = (char*)d_ws;
    float*          qws   = (float*)(ws);                       // 128 KiB
    unsigned short* uat   = (unsigned short*)(ws + 131072);     // 2 MiB
    float*          score = (float*)(ws + 131072 + 2097152);    // 256 KiB

    float* out_ctx = (float*)d_out;          // [32*1024]
    float* out_w   = out_ctx + 32*1024;      // [32*2048]

    hipMemsetAsync(score, 0, 32*2048*sizeof(float), stream);
    hipMemsetAsync(out_ctx, 0, 32*1024*sizeof(float), stream);
    pre_k<<<dim3(768), 256, 0, stream>>>(query, Wa_w, Wa_b, Ua_b, Ua_w, qws, uat);
    score_gemm_fast<<<dim3(16, 8, 32), 256, 0, stream>>>(keys, uat, qws, Va_w, score);
    softmax_k<<<dim3(32),     256, 0, stream>>>(score, out_w);
    ctx_k    <<<dim3(32, 64), 256, 0, stream>>>(keys, out_w, out_ctx, 32);
}

// Round 9
// 617.356 us; speedup vs baseline: 1.2552x; 1.2552x over previous
//
#include <hip/hip_runtime.h>
#include <hip/hip_bf16.h>

// Bahdanau attention, MI355X. B=32, S=2048, H=1024, HL=2048.
// d_out: context[32,1,1024] ++ weights[32,1,2048]  (fp32)
//
// R14 = R11 bodies (proven, 619.6us) consolidated to 3 dispatches:
//   1. pre_k: qproj + uat + ZERO score/out_ctx + kb16 (all R11-verbatim,
//      zeroing replaces the two hipMemsetAsync nodes)
//   2. score_gemm_fast: byte-identical R11 (178us, MfmaUtil 34%, 0 conflicts)
//   3. ctxsm_k: softmax recomputed per-block from score (L2-resident, bit-
//      identical out_w) + fused context accumulation (sper=32, 2048 blocks)
// Purpose: test the ~190us inter-dispatch-gap hypothesis with plain kernels
// (R13's cooperative launch failed: unsupported in this harness).
// R10/R12 fp32-A LDS layouts abandoned (bank model unreliable; only the
// bf16 quad-XOR layout is trusted).
//
// ws layout: qws 128K | uat 2M | score 256K(4M region) | 2M spare | kb16

typedef __attribute__((ext_vector_type(8))) short short8;
typedef __attribute__((ext_vector_type(4))) float floatx4;

typedef const __attribute__((address_space(1))) unsigned int gu32;
typedef __attribute__((address_space(3))) unsigned int lu32;

__device__ __forceinline__ unsigned short f2bf(float f) {
    union { float f; unsigned int u; } c; c.f = f;
    unsigned int u = c.u + 0x7fffu + ((c.u >> 16) & 1u);  // RNE
    return (unsigned short)(u >> 16);
}

__device__ __forceinline__ unsigned int f2bf2(float lo, float hi) {
#if __has_builtin(__builtin_amdgcn_cvt_pk_bf16_f32)
    auto r = __builtin_amdgcn_cvt_pk_bf16_f32(lo, hi);
    unsigned int u; __builtin_memcpy(&u, &r, 4);
    return u;
#else
    return (unsigned int)f2bf(lo) | ((unsigned int)f2bf(hi) << 16);
#endif
}

// async global->LDS, 16B per lane; lane i's data lands at ldsbase + i*16.
__device__ __forceinline__ void gld16(const unsigned short* g, unsigned short* l) {
    __builtin_amdgcn_global_load_lds(
        (gu32*)(uintptr_t)g,
        (lu32*)(unsigned int)(uintptr_t)l,
        16, 0, 0);
}

// ---- kb16 chunk conversion (proven): row s, group g, chunk c -> slot c^p,
// p=(s>>1)&3. 32B coalesced read, 16B uint4 write. ----
__device__ __forceinline__ void kb16_chunk(const float* __restrict__ keys,
                                           unsigned short* __restrict__ kb,
                                           unsigned int t)
{
    unsigned int rg  = t >> 7;
    unsigned int rem = t & 127u;
    unsigned int g   = rem >> 2;
    unsigned int c   = rem & 3u;
    unsigned int p   = ((rg & 2047u) >> 1) & 3u;
    const float4* src = reinterpret_cast<const float4*>(keys + (size_t)rg*1024 + g*32 + c*8);
    float4 v0 = src[0], v1 = src[1];
    uint4 w;
    w.x = f2bf2(v0.x, v0.y); w.y = f2bf2(v0.z, v0.w);
    w.z = f2bf2(v1.x, v1.y); w.w = f2bf2(v1.z, v1.w);
    *reinterpret_cast<uint4*>(kb + (size_t)rg*1024 + g*32 + ((c ^ p) << 3)) = w;
}

// ---- K1: fused pre-pass + zeroing ----
// blocks [0,512):    qproj
// blocks [512,768):  uat[h][d] = bf16(Ua[d][h])
// blocks [768,800):  zero score (32 x 2048 f)
// blocks [800,832):  zero out_ctx (32 x 1024 f)
// blocks [832,...):  kb16 cvt+permute (grid-stride x4)
__global__ __launch_bounds__(256) void pre_k(
    const float* __restrict__ query, const float* __restrict__ Wa,
    const float* __restrict__ Wab, const float* __restrict__ Uab,
    const float* __restrict__ Ua, const float* __restrict__ keys,
    float* __restrict__ qws, unsigned short* __restrict__ uat,
    unsigned short* __restrict__ kb, unsigned int kb_nch,
    float* __restrict__ score, float* __restrict__ out_ctx)
{
    __shared__ char smem[12288];
    const int tid = threadIdx.x;
    if (blockIdx.x < 512) {
        float* qs  = (float*)smem;          // 2048 f
        float* red = (float*)(smem + 8192); // 1024 f
        const int b = blockIdx.x >> 4, hc = blockIdx.x & 15;
        #pragma unroll
        for (int i = 0; i < 8; i++) qs[tid + 256*i] = query[b*2048 + tid + 256*i];
        __syncthreads();
        const int hq = tid & 15;      // h-quad within 64-h tile
        const int dg = tid >> 4;      // d-group (128 d each)
        const float4* wp = reinterpret_cast<const float4*>(Wa + (size_t)(dg*128)*1024 + hc*64 + hq*4);
        const float* qp = qs + dg*128;
        float4 a0; a0.x = a0.y = a0.z = a0.w = 0.f;
        float4 a1; a1.x = a1.y = a1.z = a1.w = 0.f;
        #pragma unroll 4
        for (int d = 0; d < 128; d += 2) {
            float q0 = qp[d], q1 = qp[d+1];
            float4 w0 = wp[(size_t)d*256];
            float4 w1 = wp[(size_t)(d+1)*256];
            a0.x += q0*w0.x; a0.y += q0*w0.y; a0.z += q0*w0.z; a0.w += q0*w0.w;
            a1.x += q1*w1.x; a1.y += q1*w1.y; a1.z += q1*w1.z; a1.w += q1*w1.w;
        }
        a0.x += a1.x; a0.y += a1.y; a0.z += a1.z; a0.w += a1.w;
        *reinterpret_cast<float4*>(red + dg*64 + hq*4) = a0;
        __syncthreads();
        if (tid < 64) {
            float v = 0.f;
            #pragma unroll
            for (int g = 0; g < 16; g++) v += red[g*64 + tid];
            int hh = hc*64 + tid;
            qws[b*1024 + hh] = v + Wab[hh] + Uab[hh];
        }
    } else if (blockIdx.x < 768) {
        typedef unsigned short row_t[65];
        row_t* t = (row_t*)smem;            // 64 x 65 ushort
        const int q = blockIdx.x - 512;
        const int x = tid & 63, yy = tid >> 6;
        const int d0 = (q >> 4)*64, h0 = (q & 15)*64;
        #pragma unroll
        for (int i = 0; i < 16; i++) {
            int y = yy*16 + i;
            t[y][x] = f2bf(Ua[(size_t)(d0+y)*1024 + h0 + x]);
        }
        __syncthreads();
        #pragma unroll
        for (int i = 0; i < 16; i++) {
            int y = yy*16 + i;
            uat[(size_t)(h0+y)*1024 + d0 + x] = t[x][y];
        }
    } else if (blockIdx.x < 800) {
        float* p = score + (size_t)(blockIdx.x - 768) * 2048;
        for (int i = tid; i < 2048; i += 256) p[i] = 0.f;
    } else if (blockIdx.x < 832) {
        float* p = out_ctx + (size_t)(blockIdx.x - 800) * 1024;
        for (int i = tid; i < 1024; i += 256) p[i] = 0.f;
    } else {
        const unsigned int stride = (gridDim.x - 832u) * 256u;
        unsigned int t = (blockIdx.x - 832u)*256u + tid;
        #pragma unroll 4
        for (int it = 0; it < 4; ++it, t += stride)
            if (t < kb_nch) kb16_chunk(keys, kb, t);
    }
}

// ---- standalone kb16 (fallback when workspace forces batch-chunking) ----
__global__ __launch_bounds__(256) void kb16_k(const float* __restrict__ keys,
                                              unsigned short* __restrict__ kb,
                                              unsigned int nch)
{
    const unsigned int stride = gridDim.x * 256u;
    unsigned int t = blockIdx.x * 256u + threadIdx.x;
    #pragma unroll 4
    for (int it = 0; it < 4; ++it, t += stride)
        if (t < nch) kb16_chunk(keys, kb, t);
}

// ---- K3: score GEMM 128(s) x 256(h) tile (byte-identical to R11) ----
__global__ __launch_bounds__(256) void score_gemm_fast(
    const unsigned short* __restrict__ kb16,  // [nb][2048][1024] bf16 permuted
    const unsigned short* __restrict__ uat,   // [1024][1024] bf16 [h][d]
    const float* __restrict__ qws,            // [32][1024]
    const float* __restrict__ Va,             // [1024]
    float* __restrict__ score,                // [32][2048] (pre-zeroed)
    int b0)                                   // batch offset of this chunk
{
    __shared__ unsigned short aS[2][128*32];  // 16KB
    __shared__ unsigned short bS[2][256*32];  // 32KB
    const int tid = threadIdx.x;
    const int bz = blockIdx.z;                 // local batch
    const int b = b0 + bz;                     // global batch
    const int s0 = blockIdx.x * 128;
    const int h0 = blockIdx.y * 256;
    const int lane = tid & 63, wave = tid >> 6;
    const int quad = lane >> 4, l15 = lane & 15;
    const int wm = (wave & 1) * 64, wn = (wave >> 1) * 128;

    const int srow = lane >> 2;
    const int schunk = (lane & 3) ^ ((srow >> 1) & 3);
    const unsigned short* ubase = uat + (size_t)h0*1024;
    size_t boff[4];
    #pragma unroll
    for (int u = 0; u < 4; u++) {
        int cg = wave*4 + u;                  // chunk-group 0..15 (16 rows each)
        boff[u] = (size_t)(cg*16 + srow)*1024 + schunk*8;
    }

    const unsigned short* kA = kb16 + (size_t)(bz*2048 + s0)*1024;
    const size_t aoff0 = (size_t)(tid >> 2)*1024 + (size_t)(tid & 3)*8;
    const size_t aoff1 = (size_t)(64 + (tid >> 2))*1024 + (size_t)(tid & 3)*8;

    floatx4 acc[4][8];
    #pragma unroll
    for (int i = 0; i < 4; i++)
        #pragma unroll
        for (int j = 0; j < 8; j++) acc[i][j] = (floatx4)0.0f;

    // ---- prologue: stage tile 0 into buffer 0 ----
    gld16(kA + aoff0, aS[0] + wave*512);
    gld16(kA + aoff1, aS[0] + 2048 + wave*512);
    #pragma unroll
    for (int u = 0; u < 4; u++)
        gld16(ubase + boff[u], bS[0] + (wave*4 + u)*512);
    __syncthreads();

    int cur = 0;
    for (int kt = 0; kt < 31; ++kt) {
        const int nxt = cur ^ 1;
        const int k1 = (kt + 1) << 5;

        gld16(kA + aoff0 + k1, aS[nxt] + wave*512);
        gld16(kA + aoff1 + k1, aS[nxt] + 2048 + wave*512);
        #pragma unroll
        for (int u = 0; u < 4; u++)
            gld16(ubase + boff[u] + k1, bS[nxt] + (wave*4 + u)*512);

        short8 af[4], bf8[8];
        #pragma unroll
        for (int i = 0; i < 4; i++) {
            int row = wm + 16*i + l15;
            af[i] = *reinterpret_cast<const short8*>(aS[cur] + row*32 + ((quad ^ ((row>>1)&3)) * 8));
        }
        #pragma unroll
        for (int j = 0; j < 8; j++) {
            int row = wn + 16*j + l15;
            bf8[j] = *reinterpret_cast<const short8*>(bS[cur] + row*32 + ((quad ^ ((row>>1)&3)) * 8));
        }
        #pragma unroll
        for (int i = 0; i < 4; i++)
            #pragma unroll
            for (int j = 0; j < 8; j++)
                acc[i][j] = __builtin_amdgcn_mfma_f32_16x16x32_bf16(af[i], bf8[j], acc[i][j], 0, 0, 0);

        __syncthreads();
        cur = nxt;
    }

    {
        short8 af[4], bf8[8];
        #pragma unroll
        for (int i = 0; i < 4; i++) {
            int row = wm + 16*i + l15;
            af[i] = *reinterpret_cast<const short8*>(aS[cur] + row*32 + ((quad ^ ((row>>1)&3)) * 8));
        }
        #pragma unroll
        for (int j = 0; j < 8; j++) {
            int row = wn + 16*j + l15;
            bf8[j] = *reinterpret_cast<const short8*>(bS[cur] + row*32 + ((quad ^ ((row>>1)&3)) * 8));
        }
        #pragma unroll
        for (int i = 0; i < 4; i++)
            #pragma unroll
            for (int j = 0; j < 8; j++)
                acc[i][j] = __builtin_amdgcn_mfma_f32_16x16x32_bf16(af[i], bf8[j], acc[i][j], 0, 0, 0);
    }

    float qv[8], vav[8];
    #pragma unroll
    for (int j = 0; j < 8; j++) {
        int n = h0 + wn + 16*j + l15;
        qv[j]  = qws[b*1024 + n];
        vav[j] = Va[n];
    }
    #pragma unroll
    for (int i = 0; i < 4; i++) {
        #pragma unroll
        for (int r = 0; r < 4; r++) {
            float p = 0.f;
            #pragma unroll
            for (int j = 0; j < 8; j++) {
                float x = qv[j] + acc[i][j][r];
                float e = __expf(2.f * x);                       // tanh = 1 - 2/(e^{2x}+1)
                float t = 1.f - 2.f * __builtin_amdgcn_rcpf(e + 1.f);
                p += vav[j] * t;
            }
            #pragma unroll
            for (int off = 1; off < 16; off <<= 1) p += __shfl_xor(p, off, 64);
            if (l15 == 0) {
                int m = wm + 16*i + quad*4 + r;
                atomicAdd(score + (size_t)b*2048 + s0 + m, p);
            }
        }
    }
}

// ---- K4: fused softmax + context ----
// grid (32, 64): block (b, sc) owns s-chunk [sc*32, sc*32+32).
// 1) recompute softmax stats over score[b][*] (8KB, L2-resident; bit-identical
//    math to the old softmax_k -> deterministic across blocks)
// 2) write out_w for its chunk
// 3) accumulate ctx over its 32 s-rows (float4/lane), atomicAdd into out_ctx
__global__ __launch_bounds__(256) void ctxsm_k(const float* __restrict__ keys,
                                               const float* __restrict__ score,
                                               float* __restrict__ out_w,
                                               float* __restrict__ out_ctx)
{
    const int tid = threadIdx.x;
    const int b = blockIdx.x, sc = blockIdx.y;
    __shared__ float wred[4], wred2[4], wv[32];
    float sv[8];
    float mx = -3.0e38f;
    #pragma unroll
    for (int i = 0; i < 8; i++) {
        sv[i] = score[(size_t)b*2048 + tid + 256*i];
        mx = fmaxf(mx, sv[i]);
    }
    #pragma unroll
    for (int off = 32; off >= 1; off >>= 1) mx = fmaxf(mx, __shfl_xor(mx, off, 64));
    if ((tid & 63) == 0) wred[tid >> 6] = mx;
    __syncthreads();
    mx = fmaxf(fmaxf(wred[0], wred[1]), fmaxf(wred[2], wred[3]));
    float lsum = 0.f;
    #pragma unroll
    for (int i = 0; i < 8; i++) lsum += __expf(sv[i] - mx);
    #pragma unroll
    for (int off = 32; off >= 1; off >>= 1) lsum += __shfl_xor(lsum, off, 64);
    if ((tid & 63) == 0) wred2[tid >> 6] = lsum;
    __syncthreads();
    const float inv = 1.0f / (wred2[0] + wred2[1] + wred2[2] + wred2[3]);
    if (tid < 32) {
        float e = __expf(score[(size_t)b*2048 + sc*32 + tid] - mx) * inv;
        wv[tid] = e;
        out_w[b*2048 + sc*32 + tid] = e;
    }
    __syncthreads();

    const float4* k4 = reinterpret_cast<const float4*>(keys) + (size_t)(b*2048 + sc*32)*256 + tid;
    float4 a; a.x = a.y = a.z = a.w = 0.f;
    #pragma unroll 4
    for (int s = 0; s < 32; s++) {
        float w = wv[s];
        float4 kv = k4[(size_t)s*256];
        a.x += w*kv.x; a.y += w*kv.y; a.z += w*kv.z; a.w += w*kv.w;
    }
    float* o = out_ctx + (size_t)b*1024 + tid*4;
    atomicAdd(o + 0, a.x);
    atomicAdd(o + 1, a.y);
    atomicAdd(o + 2, a.z);
    atomicAdd(o + 3, a.w);
}

extern "C" void kernel_launch(void* const* d_in, const int* in_sizes, int n_in,
                              void* d_out, int out_size, void* d_ws, size_t ws_size,
                              hipStream_t stream)
{
    const float* query = (const float*)d_in[0];
    const float* keys  = (const float*)d_in[1];
    const float* Wa_w  = (const float*)d_in[2];
    const float* Wa_b  = (const float*)d_in[3];
    const float* Ua_w  = (const float*)d_in[4];
    const float* Ua_b  = (const float*)d_in[5];
    const float* Va_w  = (const float*)d_in[6];
    // d_in[7] (Va_b) is a uniform shift on scores -> softmax-invariant; unused.

    char* ws = (char*)d_ws;
    float*          qws   = (float*)(ws);                       // 128 KiB
    unsigned short* uat   = (unsigned short*)(ws + 131072);     // 2 MiB
    float*          score = (float*)(ws + 131072 + 2097152);    // 256 KiB (4M region)
    const size_t BASE = 131072 + 2097152 + 4194304 + 2097152;   // 8.52 MiB
    unsigned short* kb16 = (unsigned short*)(ws + BASE);

    size_t avail = (ws_size > BASE) ? (ws_size - BASE) : 0;
    int nb = 32;
    while (nb > 1 && (size_t)nb * 2048 * 1024 * 2 > avail) nb >>= 1;

    float* out_ctx = (float*)d_out;          // [32*1024]
    float* out_w   = out_ctx + 32*1024;      // [32*2048]

    if (nb == 32) {
        const unsigned int nch = 32u * 2048u * 128u;            // 8.39M chunks
        pre_k<<<dim3(832 + 8192), 256, 0, stream>>>(
            query, Wa_w, Wa_b, Ua_b, Ua_w, keys, qws, uat, kb16, nch,
            score, out_ctx);
        score_gemm_fast<<<dim3(16, 4, 32), 256, 0, stream>>>(kb16, uat, qws, Va_w, score, 0);
    } else {
        pre_k<<<dim3(832), 256, 0, stream>>>(
            query, Wa_w, Wa_b, Ua_b, Ua_w, keys, qws, uat, kb16, 0u,
            score, out_ctx);
        for (int b0 = 0; b0 < 32; b0 += nb) {
            unsigned int nch = (unsigned int)nb * 2048u * 128u;
            unsigned int nblk = (nch/4u + 255u) / 256u;
            kb16_k<<<dim3(nblk), 256, 0, stream>>>(keys + (size_t)b0*2048*1024, kb16, nch);
            score_gemm_fast<<<dim3(16, 4, nb), 256, 0, stream>>>(kb16, uat, qws, Va_w, score, b0);
        }
    }
    ctxsm_k<<<dim3(32, 64), 256, 0, stream>>>(keys, score, out_w, out_ctx);
}

// Round 10
// 607.045 us; speedup vs baseline: 1.2765x; 1.0170x over previous
//
#include <hip/hip_runtime.h>
#include <hip/hip_bf16.h>

// Bahdanau attention, MI355X. B=32, S=2048, H=1024, HL=2048.
// d_out: context[32,1,1024] ++ weights[32,1,2048]  (fp32)
//
// R15: kb16 DELETED. Score GEMM keeps the proven 128(s)x256(h) tile and
// bf16 quad-XOR LDS layout, but stages A directly from fp32 keys via
// reg-staging (R6's proven-correct path: float4 loads -> cvt_pk -> swizzled
// ds_write_b128), T14-split: A-loads issued BEFORE the 32-MFMA block,
// cvt+ds_write after, one barrier per K-step. At 32 MFMA/K-step the ~30-op
// staging cost is half as significant as in R6's 16-MFMA tile.
// B (uat) staging via gld16 unchanged (proven). Epilogue unchanged.
// pre_k = qproj + uat + zeroing. ctxsm_k = fused softmax+context (R14).
// Keys HBM traffic: 732 MB (R14) -> ~446 MB.
//
// ws layout: qws 128K | uat 2M | score 256K

typedef __attribute__((ext_vector_type(8))) short short8;
typedef __attribute__((ext_vector_type(4))) float floatx4;

typedef const __attribute__((address_space(1))) unsigned int gu32;
typedef __attribute__((address_space(3))) unsigned int lu32;

__device__ __forceinline__ unsigned short f2bf(float f) {
    union { float f; unsigned int u; } c; c.f = f;
    unsigned int u = c.u + 0x7fffu + ((c.u >> 16) & 1u);  // RNE
    return (unsigned short)(u >> 16);
}

__device__ __forceinline__ unsigned int f2bf2(float lo, float hi) {
#if __has_builtin(__builtin_amdgcn_cvt_pk_bf16_f32)
    auto r = __builtin_amdgcn_cvt_pk_bf16_f32(lo, hi);
    unsigned int u; __builtin_memcpy(&u, &r, 4);
    return u;
#else
    return (unsigned int)f2bf(lo) | ((unsigned int)f2bf(hi) << 16);
#endif
}

// async global->LDS, 16B per lane; lane i's data lands at ldsbase + i*16.
__device__ __forceinline__ void gld16(const unsigned short* g, unsigned short* l) {
    __builtin_amdgcn_global_load_lds(
        (gu32*)(uintptr_t)g,
        (lu32*)(unsigned int)(uintptr_t)l,
        16, 0, 0);
}

// ---- K1: fused pre-pass + zeroing ----
// blocks [0,512):    qproj: q[b,h] = sum_d query[b,d]*Wa[d,h] + Wa_b + Ua_b
// blocks [512,768):  uat[h][d] = bf16(Ua[d][h])
// blocks [768,800):  zero score
// blocks [800,832):  zero out_ctx
__global__ __launch_bounds__(256) void pre_k(
    const float* __restrict__ query, const float* __restrict__ Wa,
    const float* __restrict__ Wab, const float* __restrict__ Uab,
    const float* __restrict__ Ua,
    float* __restrict__ qws, unsigned short* __restrict__ uat,
    float* __restrict__ score, float* __restrict__ out_ctx)
{
    __shared__ char smem[12288];
    const int tid = threadIdx.x;
    if (blockIdx.x < 512) {
        float* qs  = (float*)smem;          // 2048 f
        float* red = (float*)(smem + 8192); // 1024 f
        const int b = blockIdx.x >> 4, hc = blockIdx.x & 15;
        #pragma unroll
        for (int i = 0; i < 8; i++) qs[tid + 256*i] = query[b*2048 + tid + 256*i];
        __syncthreads();
        const int hq = tid & 15;      // h-quad within 64-h tile
        const int dg = tid >> 4;      // d-group (128 d each)
        const float4* wp = reinterpret_cast<const float4*>(Wa + (size_t)(dg*128)*1024 + hc*64 + hq*4);
        const float* qp = qs + dg*128;
        float4 a0; a0.x = a0.y = a0.z = a0.w = 0.f;
        float4 a1; a1.x = a1.y = a1.z = a1.w = 0.f;
        #pragma unroll 4
        for (int d = 0; d < 128; d += 2) {
            float q0 = qp[d], q1 = qp[d+1];
            float4 w0 = wp[(size_t)d*256];
            float4 w1 = wp[(size_t)(d+1)*256];
            a0.x += q0*w0.x; a0.y += q0*w0.y; a0.z += q0*w0.z; a0.w += q0*w0.w;
            a1.x += q1*w1.x; a1.y += q1*w1.y; a1.z += q1*w1.z; a1.w += q1*w1.w;
        }
        a0.x += a1.x; a0.y += a1.y; a0.z += a1.z; a0.w += a1.w;
        *reinterpret_cast<float4*>(red + dg*64 + hq*4) = a0;
        __syncthreads();
        if (tid < 64) {
            float v = 0.f;
            #pragma unroll
            for (int g = 0; g < 16; g++) v += red[g*64 + tid];
            int hh = hc*64 + tid;
            qws[b*1024 + hh] = v + Wab[hh] + Uab[hh];
        }
    } else if (blockIdx.x < 768) {
        typedef unsigned short row_t[65];
        row_t* t = (row_t*)smem;            // 64 x 65 ushort
        const int q = blockIdx.x - 512;
        const int x = tid & 63, yy = tid >> 6;
        const int d0 = (q >> 4)*64, h0 = (q & 15)*64;
        #pragma unroll
        for (int i = 0; i < 16; i++) {
            int y = yy*16 + i;
            t[y][x] = f2bf(Ua[(size_t)(d0+y)*1024 + h0 + x]);
        }
        __syncthreads();
        #pragma unroll
        for (int i = 0; i < 16; i++) {
            int y = yy*16 + i;
            uat[(size_t)(h0+y)*1024 + d0 + x] = t[x][y];
        }
    } else if (blockIdx.x < 800) {
        float* p = score + (size_t)(blockIdx.x - 768) * 2048;
        for (int i = tid; i < 2048; i += 256) p[i] = 0.f;
    } else {
        float* p = out_ctx + (size_t)(blockIdx.x - 800) * 1024;
        for (int i = tid; i < 1024; i += 256) p[i] = 0.f;
    }
}

// ---- K3: score GEMM 128(s) x 256(h); A reg-staged from fp32, B via gld16 ----
// LDS rows 64B (32 bf16), 16B chunks XOR-swizzled: slot = chunk ^ ((row>>1)&3)
// (the ONLY trusted layout; 0 conflicts proven R4..R14).
// A: per K-step, 4x float4 fp32 loads (issued BEFORE MFMA) -> 8x cvt_pk ->
//    2x ds_write_b128 at [row][slot] (AFTER MFMA) — R6's proven-correct path.
// B: async gld16, per-lane permuted source (proven R9).
// Double-buffered, ONE barrier per K-step; 32 MFMA/thread/K-step.
// Epilogue: tanh + Va dot + atomicAdd into score[32][2048].
__global__ __launch_bounds__(256) void score_gemm_fast(
    const float* __restrict__ keys,           // [32][2048][1024] fp32
    const unsigned short* __restrict__ uat,   // [1024][1024] bf16 [h][d]
    const float* __restrict__ qws,            // [32][1024]
    const float* __restrict__ Va,             // [1024]
    float* __restrict__ score)                // [32][2048] (pre-zeroed)
{
    __shared__ unsigned short aS[2][128*32];  // 16KB
    __shared__ unsigned short bS[2][256*32];  // 32KB
    const int tid = threadIdx.x;
    const int b  = blockIdx.z;
    const int s0 = blockIdx.x * 128;
    const int h0 = blockIdx.y * 256;
    const int lane = tid & 63, wave = tid >> 6;
    const int quad = lane >> 4, l15 = lane & 15;
    const int wm = (wave & 1) * 64, wn = (wave >> 1) * 128;

    // B-staging source (runtime-permuted, proven)
    const int srow = lane >> 2;
    const int schunk = (lane & 3) ^ ((srow >> 1) & 3);
    const unsigned short* ubase = uat + (size_t)h0*1024;
    size_t boff[4];
    #pragma unroll
    for (int u = 0; u < 4; u++) {
        int cg = wave*4 + u;                  // chunk-group 0..15 (16 rows each)
        boff[u] = (size_t)(cg*16 + srow)*1024 + schunk*8;
    }

    // A-staging constants (R6 proven): thread covers rows arow0, arow0+64;
    // 16 fp32 each at column ac*8; dest slot sl = ac ^ ((row>>1)&3).
    const float* kA = keys + (size_t)(b*2048 + s0)*1024;
    const int arow0 = tid >> 2, ac = tid & 3;

    floatx4 acc[4][8];
    #pragma unroll
    for (int i = 0; i < 4; i++)
        #pragma unroll
        for (int j = 0; j < 8; j++) acc[i][j] = (floatx4)0.0f;

    // ---- prologue: stage tile 0 into buffer 0 ----
    #pragma unroll
    for (int u = 0; u < 4; u++)
        gld16(ubase + boff[u], bS[0] + (wave*4 + u)*512);
    #pragma unroll
    for (int i = 0; i < 2; i++) {
        int row = arow0 + 64*i;
        int sl  = ac ^ ((row >> 1) & 3);
        const float* gp = kA + (size_t)row*1024 + ac*8;
        float4 v0 = *reinterpret_cast<const float4*>(gp);
        float4 v1 = *reinterpret_cast<const float4*>(gp + 4);
        uint4 w;
        w.x = f2bf2(v0.x, v0.y); w.y = f2bf2(v0.z, v0.w);
        w.z = f2bf2(v1.x, v1.y); w.w = f2bf2(v1.z, v1.w);
        *reinterpret_cast<uint4*>(aS[0] + row*32 + sl*8) = w;
    }
    __syncthreads();

    int cur = 0;
    for (int kt = 0; kt < 31; ++kt) {
        const int nxt = cur ^ 1;
        const int k1 = (kt + 1) << 5;

        // ---- prefetch tile kt+1: B async into idle LDS buffer ----
        #pragma unroll
        for (int u = 0; u < 4; u++)
            gld16(ubase + boff[u] + k1, bS[nxt] + (wave*4 + u)*512);
        // ---- prefetch tile kt+1: A fp32 into registers (consumed post-MFMA) ----
        float4 pa0[2], pa1[2];
        #pragma unroll
        for (int i = 0; i < 2; i++) {
            int row = arow0 + 64*i;
            const float* gp = kA + (size_t)row*1024 + k1 + ac*8;
            pa0[i] = *reinterpret_cast<const float4*>(gp);
            pa1[i] = *reinterpret_cast<const float4*>(gp + 4);
        }

        // ---- compute tile kt from buf cur ----
        short8 af[4], bf8[8];
        #pragma unroll
        for (int i = 0; i < 4; i++) {
            int row = wm + 16*i + l15;
            af[i] = *reinterpret_cast<const short8*>(aS[cur] + row*32 + ((quad ^ ((row>>1)&3)) * 8));
        }
        #pragma unroll
        for (int j = 0; j < 8; j++) {
            int row = wn + 16*j + l15;
            bf8[j] = *reinterpret_cast<const short8*>(bS[cur] + row*32 + ((quad ^ ((row>>1)&3)) * 8));
        }
        #pragma unroll
        for (int i = 0; i < 4; i++)
            #pragma unroll
            for (int j = 0; j < 8; j++)
                acc[i][j] = __builtin_amdgcn_mfma_f32_16x16x32_bf16(af[i], bf8[j], acc[i][j], 0, 0, 0);

        // ---- finish A(kt+1): cvt + swizzled ds_write into idle buffer ----
        #pragma unroll
        for (int i = 0; i < 2; i++) {
            int row = arow0 + 64*i;
            int sl  = ac ^ ((row >> 1) & 3);
            uint4 w;
            w.x = f2bf2(pa0[i].x, pa0[i].y); w.y = f2bf2(pa0[i].z, pa0[i].w);
            w.z = f2bf2(pa1[i].x, pa1[i].y); w.w = f2bf2(pa1[i].z, pa1[i].w);
            *reinterpret_cast<uint4*>(aS[nxt] + row*32 + sl*8) = w;
        }
        __syncthreads();   // drains B vmcnt + A ds_write + frag lgkm
        cur = nxt;
    }

    // ---- last tile: compute only ----
    {
        short8 af[4], bf8[8];
        #pragma unroll
        for (int i = 0; i < 4; i++) {
            int row = wm + 16*i + l15;
            af[i] = *reinterpret_cast<const short8*>(aS[cur] + row*32 + ((quad ^ ((row>>1)&3)) * 8));
        }
        #pragma unroll
        for (int j = 0; j < 8; j++) {
            int row = wn + 16*j + l15;
            bf8[j] = *reinterpret_cast<const short8*>(bS[cur] + row*32 + ((quad ^ ((row>>1)&3)) * 8));
        }
        #pragma unroll
        for (int i = 0; i < 4; i++)
            #pragma unroll
            for (int j = 0; j < 8; j++)
                acc[i][j] = __builtin_amdgcn_mfma_f32_16x16x32_bf16(af[i], bf8[j], acc[i][j], 0, 0, 0);
    }

    // epilogue: p[s] = sum_n Va[n]*tanh(q[n]+k[s,n]); C-layout: n=lane&15, m=quad*4+reg
    float qv[8], vav[8];
    #pragma unroll
    for (int j = 0; j < 8; j++) {
        int n = h0 + wn + 16*j + l15;
        qv[j]  = qws[b*1024 + n];
        vav[j] = Va[n];
    }
    #pragma unroll
    for (int i = 0; i < 4; i++) {
        #pragma unroll
        for (int r = 0; r < 4; r++) {
            float p = 0.f;
            #pragma unroll
            for (int j = 0; j < 8; j++) {
                float x = qv[j] + acc[i][j][r];
                float e = __expf(2.f * x);                       // tanh = 1 - 2/(e^{2x}+1)
                float t = 1.f - 2.f * __builtin_amdgcn_rcpf(e + 1.f);
                p += vav[j] * t;
            }
            #pragma unroll
            for (int off = 1; off < 16; off <<= 1) p += __shfl_xor(p, off, 64);
            if (l15 == 0) {
                int m = wm + 16*i + quad*4 + r;
                atomicAdd(score + (size_t)b*2048 + s0 + m, p);
            }
        }
    }
}

// ---- K4: fused softmax + context (proven R14) ----
// grid (32, 64): block (b, sc) owns s-chunk [sc*32, sc*32+32).
__global__ __launch_bounds__(256) void ctxsm_k(const float* __restrict__ keys,
                                               const float* __restrict__ score,
                                               float* __restrict__ out_w,
                                               float* __restrict__ out_ctx)
{
    const int tid = threadIdx.x;
    const int b = blockIdx.x, sc = blockIdx.y;
    __shared__ float wred[4], wred2[4], wv[32];
    float sv[8];
    float mx = -3.0e38f;
    #pragma unroll
    for (int i = 0; i < 8; i++) {
        sv[i] = score[(size_t)b*2048 + tid + 256*i];
        mx = fmaxf(mx, sv[i]);
    }
    #pragma unroll
    for (int off = 32; off >= 1; off >>= 1) mx = fmaxf(mx, __shfl_xor(mx, off, 64));
    if ((tid & 63) == 0) wred[tid >> 6] = mx;
    __syncthreads();
    mx = fmaxf(fmaxf(wred[0], wred[1]), fmaxf(wred[2], wred[3]));
    float lsum = 0.f;
    #pragma unroll
    for (int i = 0; i < 8; i++) lsum += __expf(sv[i] - mx);
    #pragma unroll
    for (int off = 32; off >= 1; off >>= 1) lsum += __shfl_xor(lsum, off, 64);
    if ((tid & 63) == 0) wred2[tid >> 6] = lsum;
    __syncthreads();
    const float inv = 1.0f / (wred2[0] + wred2[1] + wred2[2] + wred2[3]);
    if (tid < 32) {
        float e = __expf(score[(size_t)b*2048 + sc*32 + tid] - mx) * inv;
        wv[tid] = e;
        out_w[b*2048 + sc*32 + tid] = e;
    }
    __syncthreads();

    const float4* k4 = reinterpret_cast<const float4*>(keys) + (size_t)(b*2048 + sc*32)*256 + tid;
    float4 a; a.x = a.y = a.z = a.w = 0.f;
    #pragma unroll 4
    for (int s = 0; s < 32; s++) {
        float w = wv[s];
        float4 kv = k4[(size_t)s*256];
        a.x += w*kv.x; a.y += w*kv.y; a.z += w*kv.z; a.w += w*kv.w;
    }
    float* o = out_ctx + (size_t)b*1024 + tid*4;
    atomicAdd(o + 0, a.x);
    atomicAdd(o + 1, a.y);
    atomicAdd(o + 2, a.z);
    atomicAdd(o + 3, a.w);
}

extern "C" void kernel_launch(void* const* d_in, const int* in_sizes, int n_in,
                              void* d_out, int out_size, void* d_ws, size_t ws_size,
                              hipStream_t stream)
{
    const float* query = (const float*)d_in[0];
    const float* keys  = (const float*)d_in[1];
    const float* Wa_w  = (const float*)d_in[2];
    const float* Wa_b  = (const float*)d_in[3];
    const float* Ua_w  = (const float*)d_in[4];
    const float* Ua_b  = (const float*)d_in[5];
    const float* Va_w  = (const float*)d_in[6];
    // d_in[7] (Va_b) is a uniform shift on scores -> softmax-invariant; unused.

    char* ws = (char*)d_ws;
    float*          qws   = (float*)(ws);                       // 128 KiB
    unsigned short* uat   = (unsigned short*)(ws + 131072);     // 2 MiB
    float*          score = (float*)(ws + 131072 + 2097152);    // 256 KiB

    float* out_ctx = (float*)d_out;          // [32*1024]
    float* out_w   = out_ctx + 32*1024;      // [32*2048]

    pre_k<<<dim3(832), 256, 0, stream>>>(query, Wa_w, Wa_b, Ua_b, Ua_w,
                                         qws, uat, score, out_ctx);
    score_gemm_fast<<<dim3(16, 4, 32), 256, 0, stream>>>(keys, uat, qws, Va_w, score);
    ctxsm_k<<<dim3(32, 64), 256, 0, stream>>>(keys, score, out_w, out_ctx);
}